// Round 1
// baseline (93.069 us; speedup 1.0000x reference)
//
#include <hip/hip_runtime.h>
#include <math.h>

#define TAU_F 0.02f
#define NB 64
#define NQ 32
#define NS 256
#define ND 128
#define MAXT 12          // max 32-row tiles per doc (sum ceil(c_m/32)*32 <= 384)
#define PERMSTRIDE 384   // MAXT*32

typedef __bf16 bf16x8 __attribute__((ext_vector_type(8)));
typedef float f32x16 __attribute__((ext_vector_type(16)));

// workspace layout (bytes) — only simout + reduction scratch now
#define OFF_SIMOUT 0u          // 64*64*5*4 = 81920
#define OFF_RED    81920u      // counter @ +0, acc(float) @ +64 bytes

__device__ inline bf16x8 cvt2(float4 a, float4 b) {
    bf16x8 o;
    o[0] = (__bf16)a.x; o[1] = (__bf16)a.y; o[2] = (__bf16)a.z; o[3] = (__bf16)a.w;
    o[4] = (__bf16)b.x; o[5] = (__bf16)b.y; o[6] = (__bf16)b.z; o[7] = (__bf16)b.w;
    return o;
}

// ---------------------------------------------------------------------------
// Kernel 1 (was kernel 2): prep fused in. 512 blocks = 64 docs x 8 query-
// batches; all 8 blocks of a doc on one XCD (demb L2 reuse). Each block:
//  - ballot-based stable modality ranking (replaces prep's O(tid) loop)
//  - stages doc tiles demb->LDS with permutation + f32->bf16 on the fly,
//    same fragment layout / double-buffer pipeline as before
//  - query fragments converted straight from qemb (L2-hot)
// MFMA loop, per-wave epilogue, simout layout: UNCHANGED (validated).
// ---------------------------------------------------------------------------
__global__ __launch_bounds__(256, 2) void
main_kernel(const float* __restrict__ qemb, const float* __restrict__ demb,
            const int* __restrict__ mod, const int* __restrict__ qmask,
            float* __restrict__ simout, int* __restrict__ red) {
    int blk = blockIdx.x;              // 0..511
    int xcd = blk & 7;
    int idx = blk >> 3;                // 0..63
    int c   = xcd * 8 + (idx & 7);     // doc; 8 blocks per doc share an XCD
    int bq  = idx >> 3;                // 0..7 query-batch
    int tid = threadIdx.x;
    int lane = tid & 63, wv = tid >> 6;
    int li32 = lane & 31, kh = lane >> 5;
    int b0 = bq * 8 + wv * 2;          // this wave's 2 b's

    if (blk == 0 && tid == 0) { red[0] = 0; ((float*)red)[16] = 0.f; }

    // ---- query fragments straight from qemb (issued early, L2/L3-hot) ----
    bf16x8 bfrag[2][8];
#pragma unroll
    for (int bi = 0; bi < 2; ++bi)
#pragma unroll
        for (int kc = 0; kc < 8; ++kc) {
            const float* src = qemb + ((size_t)(b0 + bi) * NQ + li32) * ND + kc * 16 + kh * 8;
            float4 a = *(const float4*)src;
            float4 b = *(const float4*)(src + 4);
            bfrag[bi][kc] = cvt2(a, b);
        }

    // ---- per-block doc partition via wave ballots (stable rank) ----
    __shared__ int sperm[PERMSTRIDE];
    __shared__ int wcnt[4][4];                    // [wave][modality-1]
    __shared__ int counts[5], firsts[5], offs[5], padded[5];
    __shared__ int stilemod[MAXT];
    __shared__ int sT;

    int m_tok = mod[c * NS + tid];
    int rank_w = 0;
#pragma unroll
    for (int m = 1; m <= 4; ++m) {
        unsigned long long bal = __ballot(m_tok == m);
        if (lane == 0) wcnt[wv][m - 1] = __popcll(bal);
        if (m_tok == m) rank_w = __popcll(bal & ((1ull << lane) - 1ull));
    }
    __syncthreads();
    if (tid == 0) {
        int pos = 0;
        for (int m = 1; m <= 4; ++m) {
            int cnt = wcnt[0][m-1] + wcnt[1][m-1] + wcnt[2][m-1] + wcnt[3][m-1];
            counts[m] = cnt;
            offs[m] = pos;
            int p = (cnt + 31) & ~31;
            padded[m] = p;
            for (int t = pos >> 5; t < (pos + p) >> 5; ++t) stilemod[t] = m;
            pos += p;
        }
        sT = pos >> 5;
    }
    __syncthreads();
    if (m_tok) {
        int rank = rank_w;
        for (int w = 0; w < wv; ++w) rank += wcnt[w][m_tok - 1];
        sperm[offs[m_tok] + rank] = tid;
        if (rank == 0) firsts[m_tok] = tid;   // stable => rank 0 is lowest tid
    }
    __syncthreads();
    if (tid < 4) {
        int m = tid + 1;
        for (int p = counts[m]; p < padded[m]; ++p) sperm[offs[m] + p] = firsts[m];
    }
    __syncthreads();
    int T = sT;

    // ---- doc tile staging: demb -> LDS fragments, permuted, bf16 ----
    __shared__ __bf16 sbuf[2][8 * 64 * 8];   // 2 x 8 KB tile buffers
    int row = tid & 31, chunk = tid >> 5;    // thread = (doc-row-in-tile, 16-float chunk)
    const float* drow_base = demb + (size_t)c * NS * ND + chunk * 16;

    // stage tile 0
    {
        int srow = sperm[row];
        const float4* s = (const float4*)(drow_base + (size_t)srow * ND);
        float4 a0 = s[0], a1 = s[1], a2 = s[2], a3 = s[3];
        // k = chunk*16 + kh*8 + j  ->  sbuf[(chunk*64 + kh*32 + row)*8 + j]
        *(bf16x8*)&sbuf[0][((chunk * 64) + row) * 8]      = cvt2(a0, a1);
        *(bf16x8*)&sbuf[0][((chunk * 64) + 32 + row) * 8] = cvt2(a2, a3);
    }
    __syncthreads();

    float vmax[2][4];
#pragma unroll
    for (int bi = 0; bi < 2; ++bi)
#pragma unroll
        for (int m = 0; m < 4; ++m) vmax[bi][m] = -1e30f;

    int cur = 0;
    for (int t = 0; t < T; ++t) {
        // prefetch next tile rows into VGPRs (latency hidden behind MFMA)
        float4 a0, a1, a2, a3;
        bool pf = (t + 1 < T);
        if (pf) {
            int srow = sperm[(t + 1) * 32 + row];
            const float4* s = (const float4*)(drow_base + (size_t)srow * ND);
            a0 = s[0]; a1 = s[1]; a2 = s[2]; a3 = s[3];
        }

        int tm = stilemod[t];   // wave-uniform LDS broadcast
        f32x16 acc0 = {0.f,0.f,0.f,0.f,0.f,0.f,0.f,0.f,0.f,0.f,0.f,0.f,0.f,0.f,0.f,0.f};
        f32x16 acc1 = acc0;
#pragma unroll
        for (int kc = 0; kc < 8; ++kc) {
            bf16x8 af = *(const bf16x8*)&sbuf[cur][(kc * 64 + lane) * 8];
            acc0 = __builtin_amdgcn_mfma_f32_32x32x16_bf16(af, bfrag[0][kc], acc0, 0, 0, 0);
            acc1 = __builtin_amdgcn_mfma_f32_32x32x16_bf16(af, bfrag[1][kc], acc1, 0, 0, 0);
        }
        // tree reduce over 16 acc regs (short dependent chain)
        float v0 = fmaxf(fmaxf(fmaxf(acc0[0], acc0[1]),  fmaxf(acc0[2],  acc0[3])),
                         fmaxf(fmaxf(acc0[4], acc0[5]),  fmaxf(acc0[6],  acc0[7])));
        v0 = fmaxf(v0,
             fmaxf(fmaxf(fmaxf(acc0[8], acc0[9]),  fmaxf(acc0[10], acc0[11])),
                   fmaxf(fmaxf(acc0[12], acc0[13]), fmaxf(acc0[14], acc0[15]))));
        float v1 = fmaxf(fmaxf(fmaxf(acc1[0], acc1[1]),  fmaxf(acc1[2],  acc1[3])),
                         fmaxf(fmaxf(acc1[4], acc1[5]),  fmaxf(acc1[6],  acc1[7])));
        v1 = fmaxf(v1,
             fmaxf(fmaxf(fmaxf(acc1[8], acc1[9]),  fmaxf(acc1[10], acc1[11])),
                   fmaxf(fmaxf(acc1[12], acc1[13]), fmaxf(acc1[14], acc1[15]))));
        v0 = fmaxf(v0, __shfl_xor(v0, 32, 64));
        v1 = fmaxf(v1, __shfl_xor(v1, 32, 64));
        switch (tm) {
        case 1:  vmax[0][0] = fmaxf(vmax[0][0], v0); vmax[1][0] = fmaxf(vmax[1][0], v1); break;
        case 2:  vmax[0][1] = fmaxf(vmax[0][1], v0); vmax[1][1] = fmaxf(vmax[1][1], v1); break;
        case 3:  vmax[0][2] = fmaxf(vmax[0][2], v0); vmax[1][2] = fmaxf(vmax[1][2], v1); break;
        default: vmax[0][3] = fmaxf(vmax[0][3], v0); vmax[1][3] = fmaxf(vmax[1][3], v1); break;
        }

        if (pf) {
            *(bf16x8*)&sbuf[cur ^ 1][((chunk * 64) + row) * 8]      = cvt2(a0, a1);
            *(bf16x8*)&sbuf[cur ^ 1][((chunk * 64) + 32 + row) * 8] = cvt2(a2, a3);
        }
        __syncthreads();
        cur ^= 1;
    }

    // per-wave epilogue: wave owns its 2 b's end-to-end
    int q = lane & 31;
#pragma unroll
    for (int bi = 0; bi < 2; ++bi) {
        int b = b0 + bi;
        float m1 = vmax[bi][0], m2 = vmax[bi][1], m3 = vmax[bi][2], m4 = vmax[bi][3];
        float agg = fmaxf(fmaxf(m1, m2), fmaxf(m3, m4));
        float s0 = (qmask[b * NQ + q] != 0) ? agg : 0.f;
        float s1 = m1, s2 = m2, s3 = m3, s4 = m4;
#pragma unroll
        for (int off = 16; off >= 1; off >>= 1) {   // fold within 32-lane half
            s0 += __shfl_xor(s0, off, 64);
            s1 += __shfl_xor(s1, off, 64);
            s2 += __shfl_xor(s2, off, 64);
            s3 += __shfl_xor(s3, off, 64);
            s4 += __shfl_xor(s4, off, 64);
        }
        if (lane == 0) {
            float* o = simout + ((size_t)b * NB + c) * 5;   // UNNORMALIZED sums
            o[0] = s0; o[1] = s1; o[2] = s2; o[3] = s3; o[4] = s4;
        }
    }
}

// ---------------------------------------------------------------------------
// Kernel 2: loss, 64 blocks (one per row) — unchanged (validated).
// ---------------------------------------------------------------------------
__global__ __launch_bounds__(256) void
loss_kernel(const float* __restrict__ simout, const int* __restrict__ qtypes,
            const int* __restrict__ qmask, int* __restrict__ red,
            float* __restrict__ out) {
    int r = blockIdx.x;
    int tid = threadIdx.x;
    int lane = tid & 63, wv = tid >> 6;

    __shared__ float sv[320];
    for (int i = tid; i < 320; i += 256) sv[i] = simout[(size_t)r * 320 + i];

    __shared__ int scnt;
    if (wv == 0) {
        int on = (lane < NQ) ? (qmask[r * NQ + lane] != 0) : 0;
        unsigned long long bal = __ballot(on);
        if (lane == 0) scnt = __popcll(bal);
    }
    __syncthreads();
    int cq = scnt;
    float scale = 1.0f / (TAU_F * (float)(cq > 0 ? cq : 1));
    int skip = r * 5;                      // the agg-sim diagonal slot

    __shared__ float wred[4];
    float mx = -1e30f;
    for (int i = tid; i < 320; i += 256)
        if (i != skip) mx = fmaxf(mx, sv[i] * scale);
#pragma unroll
    for (int off = 32; off >= 1; off >>= 1) mx = fmaxf(mx, __shfl_xor(mx, off, 64));
    if (lane == 0) wred[wv] = mx;
    __syncthreads();
    mx = fmaxf(fmaxf(wred[0], wred[1]), fmaxf(wred[2], wred[3]));

    float sum = 0.f;
    for (int i = tid; i < 320; i += 256)
        if (i != skip) sum += expf(sv[i] * scale - mx);
#pragma unroll
    for (int off = 32; off >= 1; off >>= 1) sum += __shfl_xor(sum, off, 64);
    __syncthreads();
    if (lane == 0) wred[wv] = sum;
    __syncthreads();

    if (tid == 0) {
        float tot = wred[0] + wred[1] + wred[2] + wred[3];
        float pos = sv[r * 5 + qtypes[r]] * scale;
        float lr = (logf(tot) + mx - pos) * (1.0f / NB);
        float* acc = (float*)red + 16;
        float ret = atomicAdd(acc, lr);                  // device-coherent
        int bump = 1 + (ret > 1e37f ? 1 : 0);            // data-dep: wait ret
        int old = atomicAdd(red, bump);
        if (old == NB - 1) {
            float v = atomicAdd(acc, 0.f);               // coherent read-back
            out[0] = v;
        }
    }
}

// ---------------------------------------------------------------------------
extern "C" void kernel_launch(void* const* d_in, const int* in_sizes, int n_in,
                              void* d_out, int out_size, void* d_ws, size_t ws_size,
                              hipStream_t stream) {
    const float* qemb   = (const float*)d_in[0];
    const float* demb   = (const float*)d_in[1];
    const int*   mod    = (const int*)d_in[2];
    const int*   qtypes = (const int*)d_in[3];
    const int*   qmask  = (const int*)d_in[4];

    char* ws = (char*)d_ws;
    float* simout = (float*)(ws + OFF_SIMOUT);
    int*   red    = (int*)(ws + OFF_RED);

    main_kernel<<<512, 256, 0, stream>>>(qemb, demb, mod, qmask, simout, red);
    loss_kernel<<<NB, 256, 0, stream>>>(simout, qtypes, qmask, red, (float*)d_out);
}